// Round 1
// baseline (316.474 us; speedup 1.0000x reference)
//
#include <hip/hip_runtime.h>
#include <hip/hip_bf16.h>

// SAGAN self-attention: B=16, C=256, H=W=64, HW=4096, KEYS=1024, C8=32, C2=128
// Pipeline: prep_w -> proj (theta/phi/g GEMM) -> pool_phi/pool_g -> flash attn -> final conv+residual

typedef short short8 __attribute__((ext_vector_type(8)));
typedef float f32x4  __attribute__((ext_vector_type(4)));

#define MFMA16(a, b, c) __builtin_amdgcn_mfma_f32_16x16x32_bf16(a, b, c, 0, 0, 0)

__device__ __forceinline__ short f2bf(float f) {
    union { float f; unsigned u; } v; v.f = f;
    unsigned r = v.u + 0x7FFFu + ((v.u >> 16) & 1u);   // RNE
    return (short)(r >> 16);
}
__device__ __forceinline__ float bf2f(short s) {
    union { unsigned u; float f; } v; v.u = ((unsigned)(unsigned short)s) << 16;
    return v.f;
}

// ---------------------------------------------------------------- prep_w
// w_bf [192][256] bf16: rows 0-31 theta, 32-63 phi, 64-191 g. wf_bf [256][128].
__global__ __launch_bounds__(256) void prep_w(const float* wt, const float* wp,
                                              const float* wg, const float* wf,
                                              short* w_bf, short* wf_bf) {
    int idx = blockIdx.x * 256 + threadIdx.x;
    if (idx < 192 * 256) {
        int o = idx >> 8, c = idx & 255;
        float v = (o < 32) ? wt[o * 256 + c]
                : (o < 64) ? wp[(o - 32) * 256 + c]
                           : wg[(o - 64) * 256 + c];
        w_bf[idx] = f2bf(v);
    } else {
        int j = idx - 192 * 256;
        if (j < 256 * 128) wf_bf[j] = f2bf(wf[j]);
    }
}

// ---------------------------------------------------------------- proj
// out[o][p] = sum_c W[o][c] * x[c][p] for 64-pixel tile, all 192 out-channels.
// x staged in LDS transposed to [p][c] bf16 (pitch 264 => 16B-aligned b128 reads).
__global__ __launch_bounds__(256) void proj(const float* __restrict__ x,
                                            const short* __restrict__ w_bf,
                                            short* __restrict__ theta,
                                            short* __restrict__ phiF,
                                            short* __restrict__ gF) {
    __shared__ short xl[64 * 264];
    const int t = threadIdx.x;
    const int b = blockIdx.x >> 6;
    const int pb = (blockIdx.x & 63) << 6;
    const int p = t & 63;

    // stage: each thread packs 2 channels (c0, c0+1) for its pixel, 32 iters
    #pragma unroll
    for (int i = 0; i < 32; ++i) {
        int cp = (t >> 6) + (i << 2);          // 0..127 channel-pair index
        int c0 = cp << 1;
        float v0 = x[(b * 256 + c0) * 4096 + pb + p];
        float v1 = x[(b * 256 + c0 + 1) * 4096 + pb + p];
        unsigned pk = ((unsigned)(unsigned short)f2bf(v0)) |
                      (((unsigned)(unsigned short)f2bf(v1)) << 16);
        *(unsigned*)&xl[p * 264 + c0] = pk;
    }
    __syncthreads();

    const int lane = t & 63, w = t >> 6, G = lane >> 4, l15 = lane & 15;

    short8 af[3][8];                            // wave w owns out-rows 48w..48w+47
    #pragma unroll
    for (int j = 0; j < 3; ++j) {
        int ot = 3 * w + j;
        #pragma unroll
        for (int kt = 0; kt < 8; ++kt)
            af[j][kt] = *(const short8*)(w_bf + (16 * ot + l15) * 256 + 32 * kt + 8 * G);
    }
    f32x4 acc[3][4];
    #pragma unroll
    for (int j = 0; j < 3; ++j)
        #pragma unroll
        for (int n = 0; n < 4; ++n) acc[j][n] = (f32x4){0.f, 0.f, 0.f, 0.f};

    #pragma unroll
    for (int nt = 0; nt < 4; ++nt) {
        #pragma unroll
        for (int kt = 0; kt < 8; ++kt) {
            short8 bfr = *(const short8*)(xl + (16 * nt + l15) * 264 + 32 * kt + 8 * G);
            #pragma unroll
            for (int j = 0; j < 3; ++j)
                acc[j][nt] = MFMA16(af[j][kt], bfr, acc[j][nt]);
        }
    }

    // epilogue: D layout col=lane&15 (pixel), row=4G+r (out-channel)
    #pragma unroll
    for (int j = 0; j < 3; ++j) {
        int ot = 3 * w + j;
        #pragma unroll
        for (int nt = 0; nt < 4; ++nt) {
            int pp = pb + 16 * nt + l15;
            #pragma unroll
            for (int r = 0; r < 4; ++r) {
                int o = 16 * ot + 4 * G + r;
                short v = f2bf(acc[j][nt][r]);
                if (o < 32)      theta[(b * 4096 + pp) * 32 + o] = v;
                else if (o < 64) phiF [(b * 4096 + pp) * 32 + (o - 32)] = v;
                else             gF   [(b * 4096 + pp) * 128 + (o - 64)] = v;
            }
        }
    }
}

// ---------------------------------------------------------------- pool_phi
// phiF [b][4096][32] -> phi_t [b][1024][32] (key-major, K-contiguous for QK B-frag)
__global__ __launch_bounds__(256) void pool_phi(const short* __restrict__ phiF,
                                                short* __restrict__ phi_t) {
    int t = threadIdx.x;
    int b = blockIdx.x >> 7;
    int kg = blockIdx.x & 127;
    int c = t & 31;
    int ko = kg * 8 + (t >> 5);
    int kh = ko >> 5, kw = ko & 31;
    int p00 = kh * 128 + kw * 2;
    const short* base = phiF + (b * 4096 + p00) * 32 + c;
    float m = bf2f(base[0]);
    m = fmaxf(m, bf2f(base[32]));
    m = fmaxf(m, bf2f(base[64 * 32]));
    m = fmaxf(m, bf2f(base[65 * 32]));
    phi_t[(b * 1024 + ko) * 32 + c] = f2bf(m);
}

// ---------------------------------------------------------------- pool_g
// gF [b][4096][128] -> g_cm [b][128][1024] (channel-major, key-contiguous for PV B-frag)
__global__ __launch_bounds__(256) void pool_g(const short* __restrict__ gF,
                                              short* __restrict__ g_cm) {
    __shared__ short gp[32 * 132];
    int t = threadIdx.x;
    int b = blockIdx.x >> 5;
    int kh = blockIdx.x & 31;
    int d = t & 127;
    int half = t >> 7;
    #pragma unroll
    for (int i = 0; i < 16; ++i) {
        int kw = i * 2 + half;
        int p00 = kh * 128 + kw * 2;
        const short* base = gF + (b * 4096 + p00) * 128 + d;
        float m = bf2f(base[0]);
        m = fmaxf(m, bf2f(base[128]));
        m = fmaxf(m, bf2f(base[64 * 128]));
        m = fmaxf(m, bf2f(base[65 * 128]));
        gp[kw * 132 + d] = f2bf(m);
    }
    __syncthreads();
    int dd = t >> 1, hf = t & 1;
    short8 lo, hi;
    #pragma unroll
    for (int m2 = 0; m2 < 8; ++m2) lo[m2] = gp[(hf * 16 + m2) * 132 + dd];
    #pragma unroll
    for (int m2 = 0; m2 < 8; ++m2) hi[m2] = gp[(hf * 16 + 8 + m2) * 132 + dd];
    short* outp = g_cm + (b * 128 + dd) * 1024 + kh * 32 + hf * 16;
    *(short8*)outp = lo;
    *(short8*)(outp + 8) = hi;
}

// ---------------------------------------------------------------- flash
// Per block: 64 queries (16/wave). No max-subtraction (logits bounded ~25):
// acc += exp(S) @ G over 32-key chunks; normalize by row-sum at the end.
__global__ __launch_bounds__(256) void flash(const short* __restrict__ theta,
                                             const short* __restrict__ phi_t,
                                             const short* __restrict__ g_cm,
                                             short* __restrict__ ag) {
    __shared__ short pl[4 * 16 * 40];          // per-wave P tile, pitch 40 (16B-aligned)
    const int t = threadIdx.x;
    const int b = blockIdx.x >> 6;
    const int qb = (blockIdx.x & 63) << 6;
    const int lane = t & 63, w = t >> 6, G = lane >> 4, l15 = lane & 15;

    short8 ta = *(const short8*)(theta + ((b * 4096) + qb + 16 * w + l15) * 32 + 8 * G);

    f32x4 acc[8];
    #pragma unroll
    for (int n = 0; n < 8; ++n) acc[n] = (f32x4){0.f, 0.f, 0.f, 0.f};
    float rs[4] = {0.f, 0.f, 0.f, 0.f};
    const f32x4 z = {0.f, 0.f, 0.f, 0.f};
    short* plw = pl + w * 640;

    for (int kc = 0; kc < 32; ++kc) {
        int kb = kc * 32;
        short8 pb0 = *(const short8*)(phi_t + ((b * 1024) + kb + l15) * 32 + 8 * G);
        short8 pb1 = *(const short8*)(phi_t + ((b * 1024) + kb + 16 + l15) * 32 + 8 * G);
        f32x4 s0 = MFMA16(ta, pb0, z);
        f32x4 s1 = MFMA16(ta, pb1, z);
        #pragma unroll
        for (int r = 0; r < 4; ++r) {
            float e0 = __expf(s0[r]);
            float e1 = __expf(s1[r]);
            rs[r] += e0 + e1;
            plw[(4 * G + r) * 40 + l15] = f2bf(e0);        // D layout: row=4G+r, col=l15
            plw[(4 * G + r) * 40 + 16 + l15] = f2bf(e1);
        }
        // re-read as A-fragment: row=l15, k=8G..8G+7 (per-wave region, in-order LDS)
        short8 pa = *(const short8*)(plw + l15 * 40 + 8 * G);
        #pragma unroll
        for (int n = 0; n < 8; ++n) {
            short8 gb = *(const short8*)(g_cm + ((b * 128) + 16 * n + l15) * 1024 + kb + 8 * G);
            acc[n] = MFMA16(pa, gb, acc[n]);
        }
    }

    #pragma unroll
    for (int r = 0; r < 4; ++r) {              // row-sum across the 16 lanes of the row
        float v = rs[r];
        v += __shfl_xor(v, 1);
        v += __shfl_xor(v, 2);
        v += __shfl_xor(v, 4);
        v += __shfl_xor(v, 8);
        rs[r] = 1.0f / v;
    }
    #pragma unroll
    for (int n = 0; n < 8; ++n)
        #pragma unroll
        for (int r = 0; r < 4; ++r)
            ag[((b * 4096) + qb + 16 * w + 4 * G + r) * 128 + 16 * n + l15] =
                f2bf(acc[n][r] * rs[r]);
}

// ---------------------------------------------------------------- final conv + residual
// out[c][p] = sigma * sum_d wf[c][d]*ag[p][d] + x[c][p]
__global__ __launch_bounds__(256) void final_conv(const short* __restrict__ ag,
                                                  const short* __restrict__ wf_bf,
                                                  const float* __restrict__ x,
                                                  const float* __restrict__ sig,
                                                  float* __restrict__ out) {
    const int t = threadIdx.x;
    const int b = blockIdx.x >> 6;
    const int pb = (blockIdx.x & 63) << 6;
    const int lane = t & 63, w = t >> 6, G = lane >> 4, l15 = lane & 15;
    const float s = sig[0];

    short8 af[4][4];                            // wave w owns out-channels 64w..64w+63
    #pragma unroll
    for (int j = 0; j < 4; ++j)
        #pragma unroll
        for (int kt = 0; kt < 4; ++kt)
            af[j][kt] = *(const short8*)(wf_bf + (64 * w + 16 * j + l15) * 128 + 32 * kt + 8 * G);

    #pragma unroll
    for (int nt = 0; nt < 4; ++nt) {
        short8 bfr[4];
        #pragma unroll
        for (int kt = 0; kt < 4; ++kt)
            bfr[kt] = *(const short8*)(ag + ((b * 4096) + pb + 16 * nt + l15) * 128 + 32 * kt + 8 * G);
        f32x4 acc[4];
        #pragma unroll
        for (int j = 0; j < 4; ++j) acc[j] = (f32x4){0.f, 0.f, 0.f, 0.f};
        #pragma unroll
        for (int kt = 0; kt < 4; ++kt)
            #pragma unroll
            for (int j = 0; j < 4; ++j)
                acc[j] = MFMA16(af[j][kt], bfr[kt], acc[j]);
        #pragma unroll
        for (int j = 0; j < 4; ++j)
            #pragma unroll
            for (int r = 0; r < 4; ++r) {
                int c = 64 * w + 16 * j + 4 * G + r;
                int pp = pb + 16 * nt + l15;
                int idx = (b * 256 + c) * 4096 + pp;
                out[idx] = s * acc[j][r] + x[idx];
            }
    }
}

// ---------------------------------------------------------------- launch
extern "C" void kernel_launch(void* const* d_in, const int* in_sizes, int n_in,
                              void* d_out, int out_size, void* d_ws, size_t ws_size,
                              hipStream_t stream) {
    const float* x  = (const float*)d_in[0];
    const float* wt = (const float*)d_in[1];
    const float* wp = (const float*)d_in[2];
    const float* wg = (const float*)d_in[3];
    const float* wf = (const float*)d_in[4];
    const float* sg = (const float*)d_in[5];
    float* out = (float*)d_out;

    char* ws = (char*)d_ws;
    short* w_bf  = (short*)(ws);                  //   192*256*2 =    98304
    short* wf_bf = (short*)(ws + 98304);          //   256*128*2 =    65536
    short* theta = (short*)(ws + 163840);         // 16*4096*32*2 = 4194304
    short* phiF  = (short*)(ws + 4358144);        // 16*4096*32*2 = 4194304
    short* gF    = (short*)(ws + 8552448);        // 16*4096*128*2 = 16777216
    short* phi_t = (short*)(ws + 25329664);       // 16*1024*32*2 = 1048576
    short* g_cm  = (short*)(ws + 26378240);       // 16*128*1024*2 = 4194304
    short* ag    = (short*)(ws + 30572544);       // 16*4096*128*2 = 16777216
                                                  // total ~45.2 MB

    prep_w   <<<320,  256, 0, stream>>>(wt, wp, wg, wf, w_bf, wf_bf);
    proj     <<<1024, 256, 0, stream>>>(x, w_bf, theta, phiF, gF);
    pool_phi <<<2048, 256, 0, stream>>>(phiF, phi_t);
    pool_g   <<<512,  256, 0, stream>>>(gF, g_cm);
    flash    <<<1024, 256, 0, stream>>>(theta, phi_t, g_cm, ag);
    final_conv<<<1024,256, 0, stream>>>(ag, wf_bf, x, sg, out);
}